// Round 15
// baseline (156.115 us; speedup 1.0000x reference)
//
#include <hip/hip_runtime.h>
#include <math.h>

namespace {
constexpr int B    = 4;
constexpr int N    = 8192;
constexpr int P    = 2048;
constexpr int C    = 128;
constexpr int COUT = 256;
constexpr int NS   = 32;
constexpr int BP   = B * P;     // 8192
constexpr int BPB  = 2;         // bp per group
constexpr int GRP  = 8;         // groups per block
constexpr int NBLK = (BP / (BPB * GRP)) * 2; // 1024 blocks, n-split pairs

// ---- workspace layout (bytes, all 256-aligned) ----
constexpr size_t OFF_FEATT = 0;                          // B*N*C bf16    = 8388608
constexpr size_t OFF_WSWZ  = 8388608;                    // 40960 bf16    = 81920
constexpr size_t OFF_SSLOT = 8470528;                    // 8*6 f64       = 384 (pad 512)
constexpr size_t OFF_SUMS  = 8471040;                    // 512 f32       = 2048 (pad 4096)
constexpr size_t OFF_IDX   = 8475136;                    // 8192*32 i32   = 1048576
constexpr size_t OFF_GX    = 9523712;                    // 8192*32 u64   = 2097152
constexpr size_t OFF_YMAX  = 11620864;                   // 8192*256 f32  = 8388608
constexpr size_t WS_NEED   = 20009472;                   // ~19.1 MB
} // namespace

typedef short bf16x8 __attribute__((ext_vector_type(8)));
typedef float f32x4  __attribute__((ext_vector_type(4)));

typedef const __attribute__((address_space(1))) void gas_void;
typedef __attribute__((address_space(3))) void las_void;
#define GLOBAL_LOAD_LDS16(gp, lp) \
    __builtin_amdgcn_global_load_lds((gas_void*)(gp), (las_void*)(lp), 16, 0, 0)

__device__ inline unsigned short f2bf(float f) {
    unsigned u = __float_as_uint(f);
    unsigned r = u + 0x7fffu + ((u >> 16) & 1u);
    return (unsigned short)(r >> 16);
}

// ============ R20 ============
// R19 post-mortem: triple-buffered k_mlp looked faster in rocprof replay
// (44 vs 48us) but LIVE total regressed 148.35->153.7 (noise band +-0.7) ->
// reverted to R18's double-buffer. Replay != live; trust end-to-end.
// R20 extends the one confirmed lever (R18: 2-way index-split ballq, -3.6us):
// 4 waves per query, quarters [h*2048,(h+1)*2048). Worst-case scan 8->4
// latency-gated iterations. Exact order-preserving merge via per-quarter
// candidate lists + prefix; later quarters abort when earlier quarters are
// done with >=32 combined (acquire/release LDS flags; conservative = safe).
// Pad = rank-0 of first non-empty quarter = global first in-radius. 1 query
// per block (8192 ballq blocks, finer load balance).

// ---------------- K_A: shift BN partial stats (8 blocks) + zero sums ----------------
__global__ __launch_bounds__(256) void k_prep(const float* __restrict__ ffps,
                                              const float* __restrict__ wsh,
                                              double* __restrict__ sslot,
                                              float* __restrict__ sums) {
#pragma clang fp contract(off)
    int blk = blockIdx.x, t = threadIdx.x;
    if (blk == 8) {
        ((f32x4*)sums)[t & 127] = (f32x4){0.f, 0.f, 0.f, 0.f};  // 512 f32
        return;
    }
    __shared__ double red[6][256];
    double w[9];
#pragma unroll
    for (int i = 0; i < 9; i++) w[i] = (double)wsh[i];
    double s[3] = {0, 0, 0}, sq[3] = {0, 0, 0};
#pragma unroll
    for (int i = 0; i < 4; i++) {
        int p = blk * 1024 + t + 256 * i;
        double f0 = (double)ffps[p * 3 + 0];
        double f1 = (double)ffps[p * 3 + 1];
        double f2 = (double)ffps[p * 3 + 2];
#pragma unroll
        for (int o = 0; o < 3; o++) {
            double xo = (w[o * 3 + 0] * f0 + w[o * 3 + 1] * f1) + w[o * 3 + 2] * f2;
            s[o] += xo;
            sq[o] += xo * xo;
        }
    }
#pragma unroll
    for (int o = 0; o < 3; o++) { red[o][t] = s[o]; red[3 + o][t] = sq[o]; }
    for (int off = 128; off > 0; off >>= 1) {
        __syncthreads();
        if (t < off) {
#pragma unroll
            for (int j = 0; j < 6; j++) red[j][t] += red[j][t + off];
        }
    }
    __syncthreads();
    if (t < 6) sslot[blk * 6 + t] = red[t][0];
}

// ---------------- K_B: fused front — ballq (8192) || transpose (2048) || wswz (160) ----
__global__ __launch_bounds__(256) void k_front(const float* __restrict__ ffps,
                                               const float* __restrict__ bbxyz,
                                               const float* __restrict__ feat,
                                               const float* __restrict__ wsh,
                                               const float* __restrict__ gsh,
                                               const float* __restrict__ bsh,
                                               const float* __restrict__ wml,
                                               const double* __restrict__ sslot,
                                               unsigned short* __restrict__ featT,
                                               unsigned short* __restrict__ wswz,
                                               int* __restrict__ idxo,
                                               uint2* __restrict__ gxo) {
#pragma clang fp contract(off)
    int blk = blockIdx.x, t = threadIdx.x;
    if (blk >= 8192) {
        int rb = blk - 8192;
        if (rb < 2048) {
            // ---- transpose role: feat (B,C,N) f32 -> featT (B,N,C) bf16 ----
            __shared__ float tile[64][33];
            int tx = t & 31, ty = t >> 5;
            int n0 = (rb & 255) * 32, c0 = ((rb >> 8) & 1) * 64, b = rb >> 9;
            const float* src = feat + ((size_t)b * C + c0) * N + n0;
#pragma unroll
            for (int j = 0; j < 8; j++) tile[ty + 8 * j][tx] = src[(size_t)(ty + 8 * j) * N + tx];
            __syncthreads();
            int n = t >> 3;
            int k8 = (t & 7) * 8;
            unsigned vv[4];
#pragma unroll
            for (int i = 0; i < 4; i++) {
                unsigned lo = f2bf(tile[k8 + 2 * i][n]);
                unsigned hi = f2bf(tile[k8 + 2 * i + 1][n]);
                vv[i] = lo | (hi << 16);
            }
            *(int4*)&featT[((size_t)b * N + n0 + n) * C + c0 + k8] =
                make_int4((int)vv[0], (int)vv[1], (int)vv[2], (int)vv[3]);
        } else {
            // ---- wswz role: swizzle w_mlp into MFMA B-fragment order ----
            // wswz[rt(16)][ks(5)][lane(64)][j(8)]; element = W[rt*16+(lane&15)][k'];
            // k' = ks*32+(lane>>4)*8+j; k 0..127 -> col 3+k; 128..130 -> col 0..2.
            int i = (rb - 2048) * 256 + t;             // < 40960
            int j = i & 7;
            int lane = (i >> 3) & 63;
            int rest = i >> 9;
            int ks = rest % 5, rt = rest / 5;
            int cout = rt * 16 + (lane & 15);
            int k = ks * 32 + (lane >> 4) * 8 + j;
            float v = 0.f;
            if (k < 128) v = wml[cout * 131 + 3 + k];
            else if (k < 131) v = wml[cout * 131 + (k - 128)];
            wswz[i] = f2bf(v);
        }
        return;
    }

    // ---- ballq role: 1 query/block, split across 4 waves by index quarter ----
    __shared__ double spar[6];
    __shared__ int lidx[4][NS];                    // [quarter][rank]
    __shared__ uint2 lgx[4][NS];
    __shared__ int lcnt[4];
    __shared__ int ldone[4];
    if (t < 6) {
        double a = 0.0;
        for (int r = 0; r < 8; r++) a += sslot[r * 6 + t];
        spar[t] = a;
    }
    if (t < 4) ldone[t] = 0;
    __syncthreads();
    int half = t >> 6, lane = t & 63;              // quarter id 0..3
    int q = blk;                                   // bp index
    int b = q >> 11;                               // P = 2048
    double f0 = (double)ffps[q * 3 + 0];
    double f1 = (double)ffps[q * 3 + 1];
    double f2 = (double)ffps[q * 3 + 2];
    double qd[3];
#pragma unroll
    for (int o = 0; o < 3; o++) {
        double m  = spar[o] * (1.0 / 8192.0);      // pow2: exact, == /BP
        double v  = spar[3 + o] * (1.0 / 8192.0) - m * m;
        double is = 1.0 / sqrt(v + 1e-5);
        double x  = ((double)wsh[o * 3 + 0] * f0 + (double)wsh[o * 3 + 1] * f1) +
                    (double)wsh[o * 3 + 2] * f2;
        double y  = ((x - m) * is) * (double)gsh[o] + (double)bsh[o];
        qd[o] = (y > 0.0) ? y : 0.0;
    }
    double qx = qd[0], qy = qd[1], qz = qd[2];
    float cfx = (float)qx, cfy = (float)qy, cfz = (float)qz;
    const float* base = bbxyz + (size_t)b * N * 3;
    const double R2 = 0.8 * 0.8;
    const float R2F = 0.64f;
    // early-out: ball cannot intersect [-1,1]^3 -> zero neighbors, pad idx 0
    bool eo;
    {
        double ex = fmax(fmax(qx - 1.0, -1.0 - qx), 0.0);
        double ey = fmax(fmax(qy - 1.0, -1.0 - qy), 0.0);
        double ez = fmax(fmax(qz - 1.0, -1.0 - qz), 0.0);
        eo = (ex * ex + ey * ey + ez * ez >= R2);
    }

    if (!eo) {
        int found = 0;
        int nb = half * 2048;                      // this quarter's index base

        float X0[8], Y0[8], Z0[8], X1[8], Y1[8], Z1[8];

        auto loadb = [&](float (&XX)[8], float (&YY)[8], float (&ZZ)[8], int it) {
#pragma unroll
            for (int j = 0; j < 8; j++) {
                int n = nb + it * 512 + j * 64 + lane;
                XX[j] = base[n * 3 + 0];
                YY[j] = base[n * 3 + 1];
                ZZ[j] = base[n * 3 + 2];
            }
        };
        auto proc = [&](float (&XX)[8], float (&YY)[8], float (&ZZ)[8], int it) {
#pragma clang fp contract(off)
#pragma unroll
            for (int j = 0; j < 8; j++) {
                int n = nb + it * 512 + j * 64 + lane;
                float dxf = cfx - XX[j];
                float dyf = cfy - YY[j];
                float dzf = cfz - ZZ[j];
                float d2f = (dxf * dxf + dyf * dyf) + dzf * dzf;
                bool within;
                if (__builtin_expect(fabsf(d2f - R2F) < 1e-4f, 0)) {
                    // borderline: exact original f64 op order decides
                    double dx = qx - (double)XX[j];
                    double dy = qy - (double)YY[j];
                    double dz = qz - (double)ZZ[j];
                    within = ((dx * dx + dy * dy) + dz * dz) < R2;
                } else {
                    within = d2f < R2F;
                }
                unsigned long long mask = __ballot(within);
                if (within) {
                    int rank = found + __popcll(mask & ((1ull << lane) - 1ull));
                    if (rank < NS) {
                        lidx[half][rank] = n;
                        float rx = XX[j] - cfx, ry = YY[j] - cfy, rz = ZZ[j] - cfz;
                        unsigned u01 = (unsigned)f2bf(rx) | ((unsigned)f2bf(ry) << 16);
                        lgx[half][rank] = make_uint2(u01, (unsigned)f2bf(rz));
                    }
                }
                found += __popcll(mask);
            }
        };
        // conservative abort: all earlier quarters done AND their total >= NS
        auto earlier_full = [&]() -> bool {
            int s = 0;
#pragma unroll
            for (int h = 0; h < 4; h++) {
                if (h >= half) break;
                if (!__hip_atomic_load(&ldone[h], __ATOMIC_ACQUIRE,
                                       __HIP_MEMORY_SCOPE_WORKGROUP))
                    return false;
                s += lcnt[h];
            }
            return s >= NS;
        };

        loadb(X0, Y0, Z0, 0);
        loadb(X1, Y1, Z1, 1);

        for (int it = 0; it < 4; it += 2) {        // 512 pts per proc; quarter = 4 iters
            proc(X0, Y0, Z0, it);
            if (found >= NS) break;
            if (half > 0 && earlier_full()) break;
            loadb(X0, Y0, Z0, (it + 2 < 4) ? it + 2 : 0);
            if (it + 1 >= 4) break;
            proc(X1, Y1, Z1, it + 1);
            if (found >= NS) break;
            if (half > 0 && earlier_full()) break;
            loadb(X1, Y1, Z1, (it + 3 < 4) ? it + 3 : 0);
        }
        if (lane == 0) {
            lcnt[half] = found;
            __hip_atomic_store(&ldone[half], 1, __ATOMIC_RELEASE,
                               __HIP_MEMORY_SCOPE_WORKGROUP);
        }
    }
    __syncthreads();   // all quarters' candidate lists complete

    if (half == 0 && lane < NS) {
        if (eo) {
            idxo[q * NS + lane] = 0;
            float rx = base[0] - cfx, ry = base[1] - cfy, rz = base[2] - cfz;
            unsigned u01 = (unsigned)f2bf(rx) | ((unsigned)f2bf(ry) << 16);
            gxo[q * NS + lane] = make_uint2(u01, (unsigned)f2bf(rz));
        } else {
            // ---- order-preserving 4-way merge by prefix over raw counts ----
            int idxv = 0;
            uint2 gxv;
            bool got = false;
            int pre = 0, total = 0, h0 = -1;
#pragma unroll
            for (int h = 0; h < 4; h++) {
                int ch = lcnt[h];
                if (h0 < 0 && ch > 0) h0 = h;
                if (!got && lane < pre + ch) {
                    // lane-pre < min(ch,NS) always (lane<32, stored cap 32)
                    idxv = lidx[h][lane - pre];
                    gxv  = lgx[h][lane - pre];
                    got = true;
                }
                pre += ch;
                total += ch;
            }
            if (!got) {
                if (total > 0) {                   // pad with global-first in-radius
                    idxv = lidx[h0][0];
                    gxv  = lgx[h0][0];
                } else {                           // clips cube, zero inside: pad idx 0
                    idxv = 0;
                    float rx = base[0] - cfx, ry = base[1] - cfy, rz = base[2] - cfz;
                    unsigned u01 = (unsigned)f2bf(rx) | ((unsigned)f2bf(ry) << 16);
                    gxv = make_uint2(u01, (unsigned)f2bf(rz));
                }
            }
            idxo[q * NS + lane] = idxv;
            gxo[q * NS + lane] = gxv;
        }
    }
}

// ---------------- K_C: MFMA grouped 1x1 conv, n-split, 3 blocks/CU, XCD-swizzled ------
// (R16/R18 double-buffer form — R19's triple-buffer regressed live, reverted)
__global__ __launch_bounds__(256, 3) void k_mlp_mfma(
        const unsigned short* __restrict__ featT,
        const unsigned short* __restrict__ wswz,
        const int* __restrict__ idx,
        const uint2* __restrict__ gxyz,
        float* __restrict__ ymax,
        float* __restrict__ sums) {
    // G[buf][(mt*4+ks)*64 + lane][8]: (s = mt*16+(lane&15), k' = ks*32+(lane>>4)*8+j)
    __shared__ alignas(16) unsigned short G[2][4 * 4 * 64 * 8];   // 2 x 16KB
    int t = threadIdx.x, lane = t & 63, w = t >> 6;
    int q = lane >> 4, c16 = lane & 15;
    int d = blockIdx.x;
    int blk = ((d & 7) >> 1) * 256 + (d >> 3) * 2 + (d & 1);   // XCD-batch swizzle
    int nh = blk & 1;                              // cout half
    int bpbase = (blk >> 1) * (BPB * GRP);         // 16 bp per block pair
    const bf16x8* wp = (const bf16x8*)wswz;

    bf16x8 wreg[5][2];
#pragma unroll
    for (int ks = 0; ks < 5; ks++)
#pragma unroll
        for (int nt = 0; nt < 2; nt++)
            wreg[ks][nt] = wp[((nh * 8 + w * 2 + nt) * 5 + ks) * 64 + lane];

    int sOff = (w >> 1) * NS + (w & 1) * 16 + c16;
    size_t fb = (size_t)(bpbase >> 11) * N * C;

    int nS0 = idx[bpbase * NS + sOff] & (N - 1);
    int nS1 = idx[(bpbase + BPB) * NS + sOff] & (N - 1);
    uint2 gx_c[4] = {}, gx_n[4] = {};
    if (q == 0)
#pragma unroll
        for (int mt = 0; mt < 4; mt++)
            gx_c[mt] = gxyz[(bpbase + (mt >> 1)) * NS + (mt & 1) * 16 + c16];
    {   // stage group 0: wave w stages m-tile w
        const unsigned short* row = featT + fb + (size_t)nS0 * C + q * 8;
#pragma unroll
        for (int ks = 0; ks < 4; ks++)
            GLOBAL_LOAD_LDS16(row + ks * 32, &G[0][(w * 4 + ks) * 512]);
    }

    float smA[2] = {0.f, 0.f}, sqA[2] = {0.f, 0.f};

    for (int g = 0; g < GRP; g++) {
        int buf = g & 1;
        int bp0 = bpbase + g * BPB;
        __syncthreads();   // stage(g)+prefetch(g) drained; compute(g-1) done
        if (g + 1 < GRP) {
            const unsigned short* row = featT + fb + (size_t)nS1 * C + q * 8;
#pragma unroll
            for (int ks = 0; ks < 4; ks++)
                GLOBAL_LOAD_LDS16(row + ks * 32, &G[buf ^ 1][(w * 4 + ks) * 512]);
            if (q == 0)
#pragma unroll
                for (int mt = 0; mt < 4; mt++)
                    gx_n[mt] = gxyz[(bp0 + BPB + (mt >> 1)) * NS + (mt & 1) * 16 + c16];
        }
        if (g + 2 < GRP) nS0 = idx[(bp0 + 2 * BPB) * NS + sOff] & (N - 1);

        f32x4 acc[4][2];
#pragma unroll
        for (int mt = 0; mt < 4; mt++)
#pragma unroll
            for (int nt = 0; nt < 2; nt++) acc[mt][nt] = (f32x4){0.f, 0.f, 0.f, 0.f};

#pragma unroll
        for (int ks = 0; ks < 4; ks++) {
            bf16x8 ag[4];
#pragma unroll
            for (int mt = 0; mt < 4; mt++)
                ag[mt] = *(const bf16x8*)&G[buf][((mt * 4 + ks) * 64 + lane) * 8];
#pragma unroll
            for (int nt = 0; nt < 2; nt++)
#pragma unroll
                for (int mt = 0; mt < 4; mt++)
                    acc[mt][nt] = __builtin_amdgcn_mfma_f32_16x16x32_bf16(ag[mt], wreg[ks][nt], acc[mt][nt], 0, 0, 0);
        }
        {   // ks = 4: xyz A-frags from prefetched gxyz regs
            bf16x8 agx[4];
#pragma unroll
            for (int mt = 0; mt < 4; mt++) {
                union { int4 i; bf16x8 h; } u;
                u.i = make_int4(q == 0 ? (int)gx_c[mt].x : 0,
                                q == 0 ? (int)gx_c[mt].y : 0, 0, 0);
                agx[mt] = u.h;
            }
#pragma unroll
            for (int nt = 0; nt < 2; nt++)
#pragma unroll
                for (int mt = 0; mt < 4; mt++)
                    acc[mt][nt] = __builtin_amdgcn_mfma_f32_16x16x32_bf16(agx[mt], wreg[4][nt], acc[mt][nt], 0, 0, 0);
        }

        // epilogue: max over 32 samples (2 m-tiles) per bp; sums accumulate
#pragma unroll
        for (int pm = 0; pm < BPB; pm++) {
            int bp = bp0 + pm;
#pragma unroll
            for (int nt = 0; nt < 2; nt++) {
                f32x4 a = acc[2 * pm][nt], c = acc[2 * pm + 1][nt];
                float mx = fmaxf(fmaxf(fmaxf(a[0], a[1]), fmaxf(a[2], a[3])),
                                 fmaxf(fmaxf(c[0], c[1]), fmaxf(c[2], c[3])));
                smA[nt] += ((a[0] + a[1]) + (a[2] + a[3])) + ((c[0] + c[1]) + (c[2] + c[3]));
                sqA[nt] += ((a[0] * a[0] + a[1] * a[1]) + (a[2] * a[2] + a[3] * a[3])) +
                           ((c[0] * c[0] + c[1] * c[1]) + (c[2] * c[2] + c[3] * c[3]));
                mx = fmaxf(mx, __shfl_xor(mx, 16, 64));
                mx = fmaxf(mx, __shfl_xor(mx, 32, 64));
                if (q == 0)
                    ymax[(size_t)bp * COUT + nh * 128 + w * 32 + nt * 16 + c16] = mx;
            }
        }
        nS1 = nS0;
#pragma unroll
        for (int mt = 0; mt < 4; mt++) gx_c[mt] = gx_n[mt];
    }

#pragma unroll
    for (int nt = 0; nt < 2; nt++) {
        float sm = smA[nt], sq = sqA[nt];
        sm += __shfl_xor(sm, 16, 64);
        sm += __shfl_xor(sm, 32, 64);
        sq += __shfl_xor(sq, 16, 64);
        sq += __shfl_xor(sq, 32, 64);
        if (q == 0) {
            int cout = nh * 128 + w * 32 + nt * 16 + c16;
            atomicAdd(&sums[cout], sm);
            atomicAdd(&sums[256 + cout], sq);
        }
    }
}

// ---------------- K_D: BN params from sums, then relu(a*ymax+b), float4 ----------
__global__ __launch_bounds__(256) void k_final(const float* __restrict__ ymax,
                                               const float* __restrict__ sums,
                                               const float* __restrict__ gam,
                                               const float* __restrict__ bet,
                                               float* __restrict__ out) {
    __shared__ float sa[256], sb[256];
    int t = threadIdx.x;
    {
        double sm = (double)sums[t], sq = (double)sums[256 + t];
        double mean = sm * (1.0 / 262144.0);       // BP*NS, pow2
        double var = sq * (1.0 / 262144.0) - mean * mean;
        double a = (double)gam[t] / sqrt(var + 1e-5);
        sa[t] = (float)a;
        sb[t] = (float)((double)bet[t] - mean * a);
    }
    __syncthreads();
    int i = blockIdx.x * 256 + t;                  // float4 index, < BP*COUT/4
    int c0 = (t & 63) * 4;                         // (i&63)==(t&63) since 256%64==0
    f32x4 y = *(const f32x4*)&ymax[(size_t)i * 4];
    f32x4 r;
#pragma unroll
    for (int j = 0; j < 4; j++) r[j] = fmaxf(sa[c0 + j] * y[j] + sb[c0 + j], 0.f);
    *(f32x4*)&out[(size_t)i * 4] = r;
}

extern "C" void kernel_launch(void* const* d_in, const int* in_sizes, int n_in,
                              void* d_out, int out_size, void* d_ws, size_t ws_size,
                              hipStream_t stream) {
    const float* ffps  = (const float*)d_in[0];
    const float* bbxyz = (const float*)d_in[1];
    const float* feat  = (const float*)d_in[2];
    const float* wsh   = (const float*)d_in[3];
    const float* gsh   = (const float*)d_in[4];
    const float* bsh   = (const float*)d_in[5];
    const float* wml   = (const float*)d_in[6];
    const float* gml   = (const float*)d_in[7];
    const float* bml   = (const float*)d_in[8];
    float* out = (float*)d_out;
    char* ws = (char*)d_ws;
    if (ws_size < WS_NEED) return;

    unsigned short* featT = (unsigned short*)(ws + OFF_FEATT);
    unsigned short* wswz  = (unsigned short*)(ws + OFF_WSWZ);
    double*         sslot = (double*)(ws + OFF_SSLOT);
    float*          sums  = (float*)(ws + OFF_SUMS);
    int*            idx   = (int*)(ws + OFF_IDX);
    uint2*          gx    = (uint2*)(ws + OFF_GX);
    float*          ymax  = (float*)(ws + OFF_YMAX);

    k_prep<<<dim3(9), dim3(256), 0, stream>>>(ffps, wsh, sslot, sums);
    k_front<<<dim3(8192 + 2048 + 160), dim3(256), 0, stream>>>(
        ffps, bbxyz, feat, wsh, gsh, bsh, wml, sslot, featT, wswz, idx, gx);
    k_mlp_mfma<<<dim3(NBLK), dim3(256), 0, stream>>>(featT, wswz, idx, gx, ymax, sums);
    k_final<<<dim3(BP * COUT / 1024), dim3(256), 0, stream>>>(ymax, sums, gml, bml, out);
}

// Round 16
// 148.217 us; speedup vs baseline: 1.0533x; 1.0533x over previous
//
#include <hip/hip_runtime.h>
#include <math.h>

namespace {
constexpr int B    = 4;
constexpr int N    = 8192;
constexpr int P    = 2048;
constexpr int C    = 128;
constexpr int COUT = 256;
constexpr int NS   = 32;
constexpr int BP   = B * P;     // 8192
constexpr int BPB  = 2;         // bp per group
constexpr int GRP  = 8;         // groups per block
constexpr int NBLK = (BP / (BPB * GRP)) * 2; // 1024 blocks, n-split pairs

// ---- workspace layout (bytes, all 256-aligned) ----
constexpr size_t OFF_FEATT = 0;                          // B*N*C bf16    = 8388608
constexpr size_t OFF_WSWZ  = 8388608;                    // 40960 bf16    = 81920
constexpr size_t OFF_SSLOT = 8470528;                    // 8*6 f64       = 384 (pad 512)
constexpr size_t OFF_SUMS  = 8471040;                    // 512 f32       = 2048 (pad 4096)
constexpr size_t OFF_IDX   = 8475136;                    // 8192*32 i32   = 1048576
constexpr size_t OFF_GX    = 9523712;                    // 8192*32 u64   = 2097152
constexpr size_t OFF_YMAX  = 11620864;                   // 8192*256 f32  = 8388608
constexpr size_t WS_NEED   = 20009472;                   // ~19.1 MB
} // namespace

typedef short bf16x8 __attribute__((ext_vector_type(8)));
typedef float f32x4  __attribute__((ext_vector_type(4)));

typedef const __attribute__((address_space(1))) void gas_void;
typedef __attribute__((address_space(3))) void las_void;
#define GLOBAL_LOAD_LDS16(gp, lp) \
    __builtin_amdgcn_global_load_lds((gas_void*)(gp), (las_void*)(lp), 16, 0, 0)

__device__ inline unsigned short f2bf(float f) {
    unsigned u = __float_as_uint(f);
    unsigned r = u + 0x7fffu + ((u >> 16) & 1u);
    return (unsigned short)(r >> 16);
}

// ============ R21: restore R18 (best measured, 148.35us) ============
// Session ledger: wins = R16 (XCD-batch swizzle in k_mlp + lean 2-buffer ballq,
// -3.4us) and R18 (2-wave index-split ballq, -3.6us). Falsified levers: k_mlp
// occupancy (R9/R12), spill removal alone (R12), barrier-free reg-gather (R14,
// +16us), ballq+mlp in-kernel fusion (R15, +25us), cooperative launch (R10/R17,
// +50us+), triple-buffer stage-2-ahead (R19: faster in rocprof replay, slower
// live), 4-way ballq split (R20, +7.8us: per-block fixed costs past the
// split sweet spot). Budget at this config: harness poison-fill 44us (fixed,
// in-stream) + k_front ~36 + k_mlp ~44 + prep/final/boundaries ~24.
// k_mlp is latency-bound on ~95%-L2-cached gathers (MfmaUtil 16%, FETCH 4.2MB)
// and invariant (+-3us) across 6 structural variants; k_front's split-depth
// optimum is 2. This source = byte-exact R18.

// ---------------- K_A: shift BN partial stats (8 blocks) + zero sums ----------------
__global__ __launch_bounds__(256) void k_prep(const float* __restrict__ ffps,
                                              const float* __restrict__ wsh,
                                              double* __restrict__ sslot,
                                              float* __restrict__ sums) {
#pragma clang fp contract(off)
    int blk = blockIdx.x, t = threadIdx.x;
    if (blk == 8) {
        ((f32x4*)sums)[t & 127] = (f32x4){0.f, 0.f, 0.f, 0.f};  // 512 f32
        return;
    }
    __shared__ double red[6][256];
    double w[9];
#pragma unroll
    for (int i = 0; i < 9; i++) w[i] = (double)wsh[i];
    double s[3] = {0, 0, 0}, sq[3] = {0, 0, 0};
#pragma unroll
    for (int i = 0; i < 4; i++) {
        int p = blk * 1024 + t + 256 * i;
        double f0 = (double)ffps[p * 3 + 0];
        double f1 = (double)ffps[p * 3 + 1];
        double f2 = (double)ffps[p * 3 + 2];
#pragma unroll
        for (int o = 0; o < 3; o++) {
            double xo = (w[o * 3 + 0] * f0 + w[o * 3 + 1] * f1) + w[o * 3 + 2] * f2;
            s[o] += xo;
            sq[o] += xo * xo;
        }
    }
#pragma unroll
    for (int o = 0; o < 3; o++) { red[o][t] = s[o]; red[3 + o][t] = sq[o]; }
    for (int off = 128; off > 0; off >>= 1) {
        __syncthreads();
        if (t < off) {
#pragma unroll
            for (int j = 0; j < 6; j++) red[j][t] += red[j][t + off];
        }
    }
    __syncthreads();
    if (t < 6) sslot[blk * 6 + t] = red[t][0];
}

// ---------------- K_B: fused front — ballq (4096) || transpose (2048) || wswz (160) ----
__global__ __launch_bounds__(256) void k_front(const float* __restrict__ ffps,
                                               const float* __restrict__ bbxyz,
                                               const float* __restrict__ feat,
                                               const float* __restrict__ wsh,
                                               const float* __restrict__ gsh,
                                               const float* __restrict__ bsh,
                                               const float* __restrict__ wml,
                                               const double* __restrict__ sslot,
                                               unsigned short* __restrict__ featT,
                                               unsigned short* __restrict__ wswz,
                                               int* __restrict__ idxo,
                                               uint2* __restrict__ gxo) {
#pragma clang fp contract(off)
    int blk = blockIdx.x, t = threadIdx.x;
    if (blk >= 4096) {
        int rb = blk - 4096;
        if (rb < 2048) {
            // ---- transpose role: feat (B,C,N) f32 -> featT (B,N,C) bf16 ----
            __shared__ float tile[64][33];
            int tx = t & 31, ty = t >> 5;
            int n0 = (rb & 255) * 32, c0 = ((rb >> 8) & 1) * 64, b = rb >> 9;
            const float* src = feat + ((size_t)b * C + c0) * N + n0;
#pragma unroll
            for (int j = 0; j < 8; j++) tile[ty + 8 * j][tx] = src[(size_t)(ty + 8 * j) * N + tx];
            __syncthreads();
            int n = t >> 3;
            int k8 = (t & 7) * 8;
            unsigned vv[4];
#pragma unroll
            for (int i = 0; i < 4; i++) {
                unsigned lo = f2bf(tile[k8 + 2 * i][n]);
                unsigned hi = f2bf(tile[k8 + 2 * i + 1][n]);
                vv[i] = lo | (hi << 16);
            }
            *(int4*)&featT[((size_t)b * N + n0 + n) * C + c0 + k8] =
                make_int4((int)vv[0], (int)vv[1], (int)vv[2], (int)vv[3]);
        } else {
            // ---- wswz role: swizzle w_mlp into MFMA B-fragment order ----
            // wswz[rt(16)][ks(5)][lane(64)][j(8)]; element = W[rt*16+(lane&15)][k'];
            // k' = ks*32+(lane>>4)*8+j; k 0..127 -> col 3+k; 128..130 -> col 0..2.
            int i = (rb - 2048) * 256 + t;             // < 40960
            int j = i & 7;
            int lane = (i >> 3) & 63;
            int rest = i >> 9;
            int ks = rest % 5, rt = rest / 5;
            int cout = rt * 16 + (lane & 15);
            int k = ks * 32 + (lane >> 4) * 8 + j;
            float v = 0.f;
            if (k < 128) v = wml[cout * 131 + 3 + k];
            else if (k < 131) v = wml[cout * 131 + (k - 128)];
            wswz[i] = f2bf(v);
        }
        return;
    }

    // ---- ballq role: 2 queries/block, each split across 2 waves by index half ----
    __shared__ double spar[6];
    __shared__ int lidx[2][2][NS];                 // [query][half][rank]
    __shared__ uint2 lgx[2][2][NS];
    __shared__ int lcnt[2][2], lfirst[2][2];
    __shared__ int ldone[2];
    if (t < 6) {
        double a = 0.0;
        for (int r = 0; r < 8; r++) a += sslot[r * 6 + t];
        spar[t] = a;
    }
    if (t < 2) ldone[t] = 0;
    __syncthreads();
    int wv = t >> 6, lane = t & 63;
    int qi = wv >> 1, half = wv & 1;
    int q = blk * 2 + qi;                          // bp index
    int b = q >> 11;                               // P = 2048
    double f0 = (double)ffps[q * 3 + 0];
    double f1 = (double)ffps[q * 3 + 1];
    double f2 = (double)ffps[q * 3 + 2];
    double qd[3];
#pragma unroll
    for (int o = 0; o < 3; o++) {
        double m  = spar[o] * (1.0 / 8192.0);      // pow2: exact, == /BP
        double v  = spar[3 + o] * (1.0 / 8192.0) - m * m;
        double is = 1.0 / sqrt(v + 1e-5);
        double x  = ((double)wsh[o * 3 + 0] * f0 + (double)wsh[o * 3 + 1] * f1) +
                    (double)wsh[o * 3 + 2] * f2;
        double y  = ((x - m) * is) * (double)gsh[o] + (double)bsh[o];
        qd[o] = (y > 0.0) ? y : 0.0;
    }
    double qx = qd[0], qy = qd[1], qz = qd[2];
    float cfx = (float)qx, cfy = (float)qy, cfz = (float)qz;
    const float* base = bbxyz + (size_t)b * N * 3;
    const double R2 = 0.8 * 0.8;
    const float R2F = 0.64f;
    // early-out: ball cannot intersect [-1,1]^3 -> zero neighbors, pad idx 0
    bool eo;
    {
        double ex = fmax(fmax(qx - 1.0, -1.0 - qx), 0.0);
        double ey = fmax(fmax(qy - 1.0, -1.0 - qy), 0.0);
        double ez = fmax(fmax(qz - 1.0, -1.0 - qz), 0.0);
        eo = (ex * ex + ey * ey + ez * ez >= R2);
    }

    if (!eo) {
        int found = 0, firstn = -1;
        int nb = half * 4096;                      // this wave's index range base

        float X0[8], Y0[8], Z0[8], X1[8], Y1[8], Z1[8];

        auto loadb = [&](float (&XX)[8], float (&YY)[8], float (&ZZ)[8], int it) {
#pragma unroll
            for (int j = 0; j < 8; j++) {
                int n = nb + it * 512 + j * 64 + lane;
                XX[j] = base[n * 3 + 0];
                YY[j] = base[n * 3 + 1];
                ZZ[j] = base[n * 3 + 2];
            }
        };
        auto proc = [&](float (&XX)[8], float (&YY)[8], float (&ZZ)[8], int it) {
#pragma clang fp contract(off)
#pragma unroll
            for (int j = 0; j < 8; j++) {
                int n = nb + it * 512 + j * 64 + lane;
                float dxf = cfx - XX[j];
                float dyf = cfy - YY[j];
                float dzf = cfz - ZZ[j];
                float d2f = (dxf * dxf + dyf * dyf) + dzf * dzf;
                bool within;
                if (__builtin_expect(fabsf(d2f - R2F) < 1e-4f, 0)) {
                    // borderline: exact original f64 op order decides
                    double dx = qx - (double)XX[j];
                    double dy = qy - (double)YY[j];
                    double dz = qz - (double)ZZ[j];
                    within = ((dx * dx + dy * dy) + dz * dz) < R2;
                } else {
                    within = d2f < R2F;
                }
                unsigned long long mask = __ballot(within);
                if (firstn < 0 && mask != 0ull) firstn = (n - lane) + (__ffsll(mask) - 1);
                if (within) {
                    int rank = found + __popcll(mask & ((1ull << lane) - 1ull));
                    if (rank < NS) {
                        lidx[qi][half][rank] = n;
                        float rx = XX[j] - cfx, ry = YY[j] - cfy, rz = ZZ[j] - cfz;
                        unsigned u01 = (unsigned)f2bf(rx) | ((unsigned)f2bf(ry) << 16);
                        lgx[qi][half][rank] = make_uint2(u01, (unsigned)f2bf(rz));
                    }
                }
                found += __popcll(mask);
            }
        };

        loadb(X0, Y0, Z0, 0);
        loadb(X1, Y1, Z1, 1);

        for (int it = 0; it < 8; it += 2) {        // 512 pts per proc; half = 8 iters
            proc(X0, Y0, Z0, it);
            if (found >= NS) break;
            if (half == 1 &&
                __hip_atomic_load(&ldone[qi], __ATOMIC_RELAXED, __HIP_MEMORY_SCOPE_WORKGROUP))
                break;                              // A full: B's candidates unused
            loadb(X0, Y0, Z0, (it + 2 < 8) ? it + 2 : 0);
            if (it + 1 >= 8) break;
            proc(X1, Y1, Z1, it + 1);
            if (found >= NS) break;
            if (half == 1 &&
                __hip_atomic_load(&ldone[qi], __ATOMIC_RELAXED, __HIP_MEMORY_SCOPE_WORKGROUP))
                break;
            loadb(X1, Y1, Z1, (it + 3 < 8) ? it + 3 : 0);
        }
        if (half == 0 && found >= NS)
            __hip_atomic_store(&ldone[qi], 1, __ATOMIC_RELAXED, __HIP_MEMORY_SCOPE_WORKGROUP);
        if (lane == 0) {
            lcnt[qi][half] = found;
            lfirst[qi][half] = firstn;
        }
    }
    __syncthreads();   // all halves' candidate lists complete

    if (eo) {
        if (half == 0 && lane < NS) {
            idxo[q * NS + lane] = 0;
            float rx = base[0] - cfx, ry = base[1] - cfy, rz = base[2] - cfz;
            unsigned u01 = (unsigned)f2bf(rx) | ((unsigned)f2bf(ry) << 16);
            gxo[q * NS + lane] = make_uint2(u01, (unsigned)f2bf(rz));
        }
    } else if (half == 0 && lane < NS) {
        // ---- order-preserving merge: A's first min(fa,32), then B's first 32-fa ----
        int fa = lcnt[qi][0], fb = lcnt[qi][1];
        int ka = (fa < NS) ? fa : NS;
        int tot = fa + fb;
        int kt = (tot < NS) ? tot : NS;
        int idxv;
        uint2 gxv;
        if (lane < ka) {
            idxv = lidx[qi][0][lane];
            gxv  = lgx[qi][0][lane];
        } else if (lane < kt) {
            idxv = lidx[qi][1][lane - ka];
            gxv  = lgx[qi][1][lane - ka];
        } else if (tot > 0) {
            // pad with first in-radius point (= rank-0 candidate of the first
            // non-empty half) — same value/gx the reference produces
            int hsel = (fa > 0) ? 0 : 1;
            idxv = lidx[qi][hsel][0];
            gxv  = lgx[qi][hsel][0];
        } else {
            // ball clips cube but zero points inside: reference pads idx 0
            idxv = 0;
            float rx = base[0] - cfx, ry = base[1] - cfy, rz = base[2] - cfz;
            unsigned u01 = (unsigned)f2bf(rx) | ((unsigned)f2bf(ry) << 16);
            gxv = make_uint2(u01, (unsigned)f2bf(rz));
        }
        idxo[q * NS + lane] = idxv;
        gxo[q * NS + lane] = gxv;
    }
}

// ---------------- K_C: MFMA grouped 1x1 conv, n-split, 3 blocks/CU, XCD-swizzled ------
// (R16) bijective blockIdx remap: XCD x serves batch x>>1 only ->
// per-XCD gather working set = one 2MB featT slab, L2-resident.
__global__ __launch_bounds__(256, 3) void k_mlp_mfma(
        const unsigned short* __restrict__ featT,
        const unsigned short* __restrict__ wswz,
        const int* __restrict__ idx,
        const uint2* __restrict__ gxyz,
        float* __restrict__ ymax,
        float* __restrict__ sums) {
    // G[buf][(mt*4+ks)*64 + lane][8]: (s = mt*16+(lane&15), k' = ks*32+(lane>>4)*8+j)
    __shared__ alignas(16) unsigned short G[2][4 * 4 * 64 * 8];   // 2 x 16KB
    int t = threadIdx.x, lane = t & 63, w = t >> 6;
    int q = lane >> 4, c16 = lane & 15;
    int d = blockIdx.x;
    int blk = ((d & 7) >> 1) * 256 + (d >> 3) * 2 + (d & 1);   // XCD-batch swizzle
    int nh = blk & 1;                              // cout half
    int bpbase = (blk >> 1) * (BPB * GRP);         // 16 bp per block pair
    const bf16x8* wp = (const bf16x8*)wswz;

    bf16x8 wreg[5][2];
#pragma unroll
    for (int ks = 0; ks < 5; ks++)
#pragma unroll
        for (int nt = 0; nt < 2; nt++)
            wreg[ks][nt] = wp[((nh * 8 + w * 2 + nt) * 5 + ks) * 64 + lane];

    int sOff = (w >> 1) * NS + (w & 1) * 16 + c16;
    size_t fb = (size_t)(bpbase >> 11) * N * C;

    int nS0 = idx[bpbase * NS + sOff] & (N - 1);
    int nS1 = idx[(bpbase + BPB) * NS + sOff] & (N - 1);
    uint2 gx_c[4] = {}, gx_n[4] = {};
    if (q == 0)
#pragma unroll
        for (int mt = 0; mt < 4; mt++)
            gx_c[mt] = gxyz[(bpbase + (mt >> 1)) * NS + (mt & 1) * 16 + c16];
    {   // stage group 0: wave w stages m-tile w
        const unsigned short* row = featT + fb + (size_t)nS0 * C + q * 8;
#pragma unroll
        for (int ks = 0; ks < 4; ks++)
            GLOBAL_LOAD_LDS16(row + ks * 32, &G[0][(w * 4 + ks) * 512]);
    }

    float smA[2] = {0.f, 0.f}, sqA[2] = {0.f, 0.f};

    for (int g = 0; g < GRP; g++) {
        int buf = g & 1;
        int bp0 = bpbase + g * BPB;
        __syncthreads();   // stage(g)+prefetch(g) drained; compute(g-1) done
        if (g + 1 < GRP) {
            const unsigned short* row = featT + fb + (size_t)nS1 * C + q * 8;
#pragma unroll
            for (int ks = 0; ks < 4; ks++)
                GLOBAL_LOAD_LDS16(row + ks * 32, &G[buf ^ 1][(w * 4 + ks) * 512]);
            if (q == 0)
#pragma unroll
                for (int mt = 0; mt < 4; mt++)
                    gx_n[mt] = gxyz[(bp0 + BPB + (mt >> 1)) * NS + (mt & 1) * 16 + c16];
        }
        if (g + 2 < GRP) nS0 = idx[(bp0 + 2 * BPB) * NS + sOff] & (N - 1);

        f32x4 acc[4][2];
#pragma unroll
        for (int mt = 0; mt < 4; mt++)
#pragma unroll
            for (int nt = 0; nt < 2; nt++) acc[mt][nt] = (f32x4){0.f, 0.f, 0.f, 0.f};

#pragma unroll
        for (int ks = 0; ks < 4; ks++) {
            bf16x8 ag[4];
#pragma unroll
            for (int mt = 0; mt < 4; mt++)
                ag[mt] = *(const bf16x8*)&G[buf][((mt * 4 + ks) * 64 + lane) * 8];
#pragma unroll
            for (int nt = 0; nt < 2; nt++)
#pragma unroll
                for (int mt = 0; mt < 4; mt++)
                    acc[mt][nt] = __builtin_amdgcn_mfma_f32_16x16x32_bf16(ag[mt], wreg[ks][nt], acc[mt][nt], 0, 0, 0);
        }
        {   // ks = 4: xyz A-frags from prefetched gxyz regs
            bf16x8 agx[4];
#pragma unroll
            for (int mt = 0; mt < 4; mt++) {
                union { int4 i; bf16x8 h; } u;
                u.i = make_int4(q == 0 ? (int)gx_c[mt].x : 0,
                                q == 0 ? (int)gx_c[mt].y : 0, 0, 0);
                agx[mt] = u.h;
            }
#pragma unroll
            for (int nt = 0; nt < 2; nt++)
#pragma unroll
                for (int mt = 0; mt < 4; mt++)
                    acc[mt][nt] = __builtin_amdgcn_mfma_f32_16x16x32_bf16(agx[mt], wreg[4][nt], acc[mt][nt], 0, 0, 0);
        }

        // epilogue: max over 32 samples (2 m-tiles) per bp; sums accumulate
#pragma unroll
        for (int pm = 0; pm < BPB; pm++) {
            int bp = bp0 + pm;
#pragma unroll
            for (int nt = 0; nt < 2; nt++) {
                f32x4 a = acc[2 * pm][nt], c = acc[2 * pm + 1][nt];
                float mx = fmaxf(fmaxf(fmaxf(a[0], a[1]), fmaxf(a[2], a[3])),
                                 fmaxf(fmaxf(c[0], c[1]), fmaxf(c[2], c[3])));
                smA[nt] += ((a[0] + a[1]) + (a[2] + a[3])) + ((c[0] + c[1]) + (c[2] + c[3]));
                sqA[nt] += ((a[0] * a[0] + a[1] * a[1]) + (a[2] * a[2] + a[3] * a[3])) +
                           ((c[0] * c[0] + c[1] * c[1]) + (c[2] * c[2] + c[3] * c[3]));
                mx = fmaxf(mx, __shfl_xor(mx, 16, 64));
                mx = fmaxf(mx, __shfl_xor(mx, 32, 64));
                if (q == 0)
                    ymax[(size_t)bp * COUT + nh * 128 + w * 32 + nt * 16 + c16] = mx;
            }
        }
        nS1 = nS0;
#pragma unroll
        for (int mt = 0; mt < 4; mt++) gx_c[mt] = gx_n[mt];
    }

#pragma unroll
    for (int nt = 0; nt < 2; nt++) {
        float sm = smA[nt], sq = sqA[nt];
        sm += __shfl_xor(sm, 16, 64);
        sm += __shfl_xor(sm, 32, 64);
        sq += __shfl_xor(sq, 16, 64);
        sq += __shfl_xor(sq, 32, 64);
        if (q == 0) {
            int cout = nh * 128 + w * 32 + nt * 16 + c16;
            atomicAdd(&sums[cout], sm);
            atomicAdd(&sums[256 + cout], sq);
        }
    }
}

// ---------------- K_D: BN params from sums, then relu(a*ymax+b), float4 ----------
__global__ __launch_bounds__(256) void k_final(const float* __restrict__ ymax,
                                               const float* __restrict__ sums,
                                               const float* __restrict__ gam,
                                               const float* __restrict__ bet,
                                               float* __restrict__ out) {
    __shared__ float sa[256], sb[256];
    int t = threadIdx.x;
    {
        double sm = (double)sums[t], sq = (double)sums[256 + t];
        double mean = sm * (1.0 / 262144.0);       // BP*NS, pow2
        double var = sq * (1.0 / 262144.0) - mean * mean;
        double a = (double)gam[t] / sqrt(var + 1e-5);
        sa[t] = (float)a;
        sb[t] = (float)((double)bet[t] - mean * a);
    }
    __syncthreads();
    int i = blockIdx.x * 256 + t;                  // float4 index, < BP*COUT/4
    int c0 = (t & 63) * 4;                         // (i&63)==(t&63) since 256%64==0
    f32x4 y = *(const f32x4*)&ymax[(size_t)i * 4];
    f32x4 r;
#pragma unroll
    for (int j = 0; j < 4; j++) r[j] = fmaxf(sa[c0 + j] * y[j] + sb[c0 + j], 0.f);
    *(f32x4*)&out[(size_t)i * 4] = r;
}

extern "C" void kernel_launch(void* const* d_in, const int* in_sizes, int n_in,
                              void* d_out, int out_size, void* d_ws, size_t ws_size,
                              hipStream_t stream) {
    const float* ffps  = (const float*)d_in[0];
    const float* bbxyz = (const float*)d_in[1];
    const float* feat  = (const float*)d_in[2];
    const float* wsh   = (const float*)d_in[3];
    const float* gsh   = (const float*)d_in[4];
    const float* bsh   = (const float*)d_in[5];
    const float* wml   = (const float*)d_in[6];
    const float* gml   = (const float*)d_in[7];
    const float* bml   = (const float*)d_in[8];
    float* out = (float*)d_out;
    char* ws = (char*)d_ws;
    if (ws_size < WS_NEED) return;

    unsigned short* featT = (unsigned short*)(ws + OFF_FEATT);
    unsigned short* wswz  = (unsigned short*)(ws + OFF_WSWZ);
    double*         sslot = (double*)(ws + OFF_SSLOT);
    float*          sums  = (float*)(ws + OFF_SUMS);
    int*            idx   = (int*)(ws + OFF_IDX);
    uint2*          gx    = (uint2*)(ws + OFF_GX);
    float*          ymax  = (float*)(ws + OFF_YMAX);

    k_prep<<<dim3(9), dim3(256), 0, stream>>>(ffps, wsh, sslot, sums);
    k_front<<<dim3(4096 + 2048 + 160), dim3(256), 0, stream>>>(
        ffps, bbxyz, feat, wsh, gsh, bsh, wml, sslot, featT, wswz, idx, gx);
    k_mlp_mfma<<<dim3(NBLK), dim3(256), 0, stream>>>(featT, wswz, idx, gx, ymax, sums);
    k_final<<<dim3(BP * COUT / 1024), dim3(256), 0, stream>>>(ymax, sums, gml, bml, out);
}